// Round 14
// baseline (214.179 us; speedup 1.0000x reference)
//
#include <hip/hip_runtime.h>
#include <stdint.h>

typedef __bf16 bf16x8 __attribute__((ext_vector_type(8)));
typedef float f32x4 __attribute__((ext_vector_type(4)));
typedef float f32x16 __attribute__((ext_vector_type(16)));

static constexpr int BB = 4, TT = 2048, CC = 1024, HH = 16, DH = 64;
static constexpr int MM = BB * TT;   // 8192
static constexpr int N1 = 3 * CC;    // 3072
static constexpr int KK = CC;        // 1024

__device__ __forceinline__ unsigned short f2bf(float f) {
  uint32_t u = __builtin_bit_cast(uint32_t, f);
  u += 0x7FFFu + ((u >> 16) & 1u);
  return (unsigned short)(u >> 16);
}

__device__ __forceinline__ void async16(const void* g, void* l) {
  __builtin_amdgcn_global_load_lds((const __attribute__((address_space(1))) void*)g,
                                   (__attribute__((address_space(3))) void*)l, 16, 0, 0);
}

// ---- f32 -> bf16, 8 elems/thread ----
__global__ __launch_bounds__(256) void k_cvt(const float* __restrict__ src,
                                             unsigned short* __restrict__ dst) {
  int i = blockIdx.x * 256 + threadIdx.x;
  const float4* s = (const float4*)src + (size_t)i * 2;
  float4 a = s[0], b = s[1];
  union { unsigned short h[8]; uint4 v; } o;
  o.h[0] = f2bf(a.x); o.h[1] = f2bf(a.y); o.h[2] = f2bf(a.z); o.h[3] = f2bf(a.w);
  o.h[4] = f2bf(b.x); o.h[5] = f2bf(b.y); o.h[6] = f2bf(b.z); o.h[7] = f2bf(b.w);
  ((uint4*)dst)[i] = o.v;
}

// ---- transpose + convert: src[R][C] f32 -> dst[C][R] bf16 ----
__global__ __launch_bounds__(256) void k_tcvt(const float* __restrict__ src,
                                              unsigned short* __restrict__ dst,
                                              int R, int C) {
  __shared__ float tile[32][33];
  int tx = threadIdx.x & 31, ty = threadIdx.x >> 5;
  int c0 = blockIdx.x * 32, r0 = blockIdx.y * 32;
#pragma unroll
  for (int i = 0; i < 4; ++i)
    tile[ty + i * 8][tx] = src[(size_t)(r0 + ty + i * 8) * C + c0 + tx];
  __syncthreads();
#pragma unroll
  for (int i = 0; i < 4; ++i)
    dst[(size_t)(c0 + ty + i * 8) * R + r0 + tx] = f2bf(tile[tx][ty + i * 8]);
}

// ============ 256x128 4-phase GEMM (T1+T2+T3+T4+T5), 96KB LDS ============
#define LDA4(Ab, mf, ksl) \
  (*(const bf16x8*)&(Ab)[(wm * 128 + (mf) * 16 + l15) * 64 + \
                         ((((ksl) * 4 + l16) ^ (l15 & 7)) * 8)])
#define LDB4(Bb, nf, ksl) \
  (*(const bf16x8*)&(Bb)[(wn * 32 + (nf) * 16 + l15) * 64 + \
                         ((((ksl) * 4 + l16) ^ (l15 & 7)) * 8)])

struct AF8 { bf16x8 a[8]; };

template <int P, bool LOADB>
__device__ __forceinline__ AF8 phase_pre4(const unsigned short* Ab, const unsigned short* Bb,
                                          int wm, int wn, int l15, int l16, bf16x8* bfr) {
  AF8 f;
#pragma unroll
  for (int mf = 0; mf < 4; ++mf) {
    f.a[mf * 2] = LDA4(Ab, P * 4 + mf, 0);
    f.a[mf * 2 + 1] = LDA4(Ab, P * 4 + mf, 1);
  }
  if (LOADB) {
#pragma unroll
    for (int nf = 0; nf < 2; ++nf) {
      bfr[nf * 2] = LDB4(Bb, nf, 0);
      bfr[nf * 2 + 1] = LDB4(Bb, nf, 1);
    }
  }
  return f;
}

template <int P>
__device__ __forceinline__ void phase_mfma4(const AF8& f, const bf16x8* bfr, f32x4 acc[8][2]) {
#pragma unroll
  for (int mf = 0; mf < 4; ++mf)
#pragma unroll
    for (int nf = 0; nf < 2; ++nf) {
      acc[P * 4 + mf][nf] = __builtin_amdgcn_mfma_f32_16x16x32_bf16(
          f.a[mf * 2], bfr[nf * 2], acc[P * 4 + mf][nf], 0, 0, 0);
      acc[P * 4 + mf][nf] = __builtin_amdgcn_mfma_f32_16x16x32_bf16(
          f.a[mf * 2 + 1], bfr[nf * 2 + 1], acc[P * 4 + mf][nf], 0, 0, 0);
    }
}

#define PHASE4(P, AB, BB_, LOADB, STAGES, WAITS)                      \
  { AF8 f_ = phase_pre4<P, LOADB>(AB, BB_, wm, wn, l15, l16, bfr);    \
    STAGES;                                                           \
    WAITS;                                                            \
    __builtin_amdgcn_s_barrier();                                     \
    asm volatile("s_waitcnt lgkmcnt(0)" ::: "memory");                \
    __builtin_amdgcn_sched_barrier(0);                                \
    __builtin_amdgcn_s_setprio(1);                                    \
    phase_mfma4<P>(f_, bfr, acc);                                     \
    __builtin_amdgcn_s_setprio(0);                                    \
    __builtin_amdgcn_s_barrier(); }

template <int MODE, int NBX>
__global__ __launch_bounds__(512, 2) void k_gemm4(
    const unsigned short* __restrict__ A, const unsigned short* __restrict__ Bt,
    const float* __restrict__ bias, int M, int N, int K,
    unsigned short* __restrict__ qo, unsigned short* __restrict__ ko,
    unsigned short* __restrict__ vo, float* __restrict__ fo) {
  __shared__ __attribute__((aligned(16))) unsigned short lds[49152];  // 96 KB
  unsigned short* As0 = lds;           // [256][64]
  unsigned short* As1 = lds + 16384;
  unsigned short* Bs0 = lds + 32768;   // [128][64]
  unsigned short* Bs1 = lds + 40960;

  const int tid = threadIdx.x;
  const int lane = tid & 63;
  const int w = tid >> 6, wm = w >> 2, wn = w & 3;
  const int l15 = lane & 15, l16 = lane >> 4;

  const int q8 = (int)gridDim.x >> 3;
  const int swz = ((int)blockIdx.x & 7) * q8 + ((int)blockIdx.x >> 3);
  const int m0 = (swz / NBX) * 256, n0 = (swz % NBX) * 128;

  f32x4 acc[8][2] = {};

  const int srow = tid >> 3;                       // 0..63
  const int sg = ((tid & 7) ^ (srow & 7)) * 8;
  const int dOff = srow * 64 + (tid & 7) * 8;
  const unsigned short* aBase = A + (size_t)(m0 + srow) * K + sg;
  const unsigned short* bBase = Bt + (size_t)(n0 + srow) * K + sg;

#define STAGE_A(dst, kt, h)                                                          \
  { async16(aBase + (size_t)((h) * 128) * K + (kt) * 64, (dst) + (h) * 8192 + dOff); \
    async16(aBase + (size_t)((h) * 128 + 64) * K + (kt) * 64,                        \
            (dst) + (h) * 8192 + 4096 + dOff); }
#define STAGE_B(dst, kt)                                                             \
  { async16(bBase + (kt) * 64, (dst) + dOff);                                        \
    async16(bBase + (size_t)64 * K + (kt) * 64, (dst) + 4096 + dOff); }

  STAGE_A(As0, 0, 0); STAGE_A(As0, 0, 1);
  STAGE_B(Bs0, 0);
  STAGE_B(Bs1, 1);
  asm volatile("s_waitcnt vmcnt(0)" ::: "memory");
  __builtin_amdgcn_s_barrier();

  const int NITER = K / 128;
#pragma unroll 1
  for (int i = 0; i < NITER; ++i) {
    const bool more = (i + 1 < NITER);
    const int tb = 2 * i + 1, t2k = 2 * i + 2, t3 = 2 * i + 3;
    bf16x8 bfr[4];
    PHASE4(0, As0, Bs0, true,
           { STAGE_A(As1, tb, 0); STAGE_A(As1, tb, 1); }, ((void)0));
    PHASE4(1, As0, Bs0, false,
           { if (more) STAGE_B(Bs0, t2k); },
           { if (more) { asm volatile("s_waitcnt vmcnt(2)" ::: "memory"); }
             else      { asm volatile("s_waitcnt vmcnt(0)" ::: "memory"); } });
    PHASE4(0, As1, Bs1, true,
           { if (more) { STAGE_A(As0, t2k, 0); STAGE_A(As0, t2k, 1); } }, ((void)0));
    PHASE4(1, As1, Bs1, false,
           { if (more) STAGE_B(Bs1, t3); },
           { if (more) { asm volatile("s_waitcnt vmcnt(2)" ::: "memory"); } });
  }

  // ---- epilogue ----
  if (MODE == 0) {
    const int sel = n0 >> 10;
    if (sel < 2) {
      const float qs = (sel == 0) ? 0.180336892f : 1.0f;
      float bj[2];
#pragma unroll
      for (int nf = 0; nf < 2; ++nf) bj[nf] = bias[n0 + wn * 32 + nf * 16 + l15];
#pragma unroll
      for (int mf = 0; mf < 8; ++mf)
#pragma unroll
        for (int nf = 0; nf < 2; ++nf)
#pragma unroll
          for (int r = 0; r < 4; ++r) {
            const int row = wm * 128 + mf * 16 + l16 * 4 + r;
            const int col = wn * 32 + nf * 16 + l15;
            lds[row * 128 + (col >> 6) * 64 +
                ((((col >> 3) & 7) ^ (row & 7)) * 8) + (col & 7)] =
                f2bf((acc[mf][nf][r] + bj[nf]) * qs);
          }
      __syncthreads();
      const int row = tid >> 1, half = tid & 1;
      const int gm = m0 + row, bb2 = gm >> 11, t2 = gm & 2047;
      const int h2 = ((n0 & 1023) >> 6) + half;
      unsigned short* dst = (sel == 0 ? qo : ko) +
          ((size_t)(bb2 * HH + h2) * TT + t2) * DH;
#pragma unroll
      for (int g = 0; g < 8; ++g) {
        bf16x8 v = *(const bf16x8*)&lds[row * 128 + half * 64 + ((g ^ (row & 7)) * 8)];
        *(bf16x8*)&dst[g * 8] = v;
      }
    } else {
#pragma unroll
      for (int mf = 0; mf < 8; ++mf)
#pragma unroll
        for (int nf = 0; nf < 2; ++nf) {
          const int gn = n0 + wn * 32 + nf * 16 + l15;
          const float bj = bias[gn];
          const int h = (gn & 1023) >> 6, d = gn & 63;
          const int gm0 = m0 + wm * 128 + mf * 16 + l16 * 4;
          const int bb2 = gm0 >> 11, t0 = gm0 & 2047;
          union { unsigned short s[4]; uint2 u; } pk;
#pragma unroll
          for (int r = 0; r < 4; ++r) pk.s[r] = f2bf(acc[mf][nf][r] + bj);
          *(uint2*)&vo[((size_t)(bb2 * HH + h) * DH + d) * TT + t0] = pk.u;
        }
    }
  } else {
#pragma unroll
    for (int mf = 0; mf < 8; ++mf)
#pragma unroll
      for (int nf = 0; nf < 2; ++nf) {
        const int gn = n0 + wn * 32 + nf * 16 + l15;
        const float bj = bias[gn];
#pragma unroll
        for (int r = 0; r < 4; ++r) {
          const int gm = m0 + wm * 128 + mf * 16 + l16 * 4 + r;
          fo[(size_t)gm * N + gn] = acc[mf][nf][r] + bj;
        }
      }
  }
#undef STAGE_A
#undef STAGE_B
}

// ---- flash attention, swapped-QK^T 32x32, fixed-max softmax ----
// r10 inner code EXACTLY; only change: KVBLK=128 per barrier period.
// Ks[4]/Vs[4] sub-buffers (64KB LDS, 2 blocks/CU unchanged); each iteration
// stages two 64-kv sub-tiles and computes both between ONE pair of barriers.
// Barriers: 16 vs 32 -> halves the per-tile wave-convergence loss; the 8
// in-flight staging loads hide under a 2x longer compute shadow.
__global__ __launch_bounds__(256, 2) void k_attn(
    const unsigned short* __restrict__ Q,   // [64][T][64] bh-major, scale=0.125*log2e
    const unsigned short* __restrict__ Kx,  // [64][T][64]
    const unsigned short* __restrict__ Vt,  // [64][64][T]  (d-major)
    unsigned short* __restrict__ At,        // [B][T][C]
    float neg16) {
  __shared__ __attribute__((aligned(16))) unsigned short Ks[4][64 * 64];  // 32 KB
  __shared__ __attribute__((aligned(16))) unsigned short Vs[4][64 * 64];  // 32 KB
  const int tid = threadIdx.x, lane = tid & 63, w = tid >> 6;
  const int l31 = lane & 31, hi5 = lane >> 5;
  const int id = blockIdx.x;
  const int bh = (id & 7) + ((id >> 7) << 3);
  const int qb = (id >> 3) & 15;
  const int q0 = qb * 128 + w * 32;
  const unsigned short* Qp = Q + (size_t)bh * TT * DH;
  const unsigned short* Kp = Kx + (size_t)bh * TT * DH;
  const unsigned short* Vp = Vt + (size_t)bh * DH * TT;

  bf16x8 qf[4];
#pragma unroll
  for (int j = 0; j < 4; ++j)
    qf[j] = *(const bf16x8*)&Qp[(size_t)(q0 + l31) * DH + j * 16 + hi5 * 8];

  f32x16 cinit;
#pragma unroll
  for (int r = 0; r < 16; ++r) cinit[r] = neg16;

  const int srow = tid >> 3;
  const int sg = ((tid & 7) ^ (srow & 7)) * 8;

  float l8[8];
#pragma unroll
  for (int r = 0; r < 8; ++r) l8[r] = 0.f;
  f32x16 oacc[2] = {};

  // prologue: stage kv tile 0 (128 rows) into sub-buffers 0,1
#pragma unroll
  for (int h = 0; h < 2; ++h)
#pragma unroll
    for (int i = 0; i < 2; ++i) {
      async16(Kp + (size_t)(h * 64 + i * 32 + srow) * DH + sg,
              &Ks[h][i * 2048 + tid * 8]);
      async16(Vp + (size_t)(i * 32 + srow) * TT + h * 64 + sg,
              &Vs[h][i * 2048 + tid * 8]);
    }
  __syncthreads();

#pragma unroll 2
  for (int kt = 0; kt < TT / 128; ++kt) {
    const int cur = kt & 1;
    if (kt + 1 < TT / 128) {
      const int kv1 = (kt + 1) * 128;
#pragma unroll
      for (int h = 0; h < 2; ++h)
#pragma unroll
        for (int i = 0; i < 2; ++i) {
          async16(Kp + (size_t)(kv1 + h * 64 + i * 32 + srow) * DH + sg,
                  &Ks[(cur ^ 1) * 2 + h][i * 2048 + tid * 8]);
          async16(Vp + (size_t)(i * 32 + srow) * TT + kv1 + h * 64 + sg,
                  &Vs[(cur ^ 1) * 2 + h][i * 2048 + tid * 8]);
        }
    }

#pragma unroll
    for (int h = 0; h < 2; ++h) {
      const unsigned short* Kb_ = Ks[cur * 2 + h];
      const unsigned short* Vb_ = Vs[cur * 2 + h];

      f32x16 sacc[2];
      __builtin_amdgcn_s_setprio(1);
#pragma unroll
      for (int t = 0; t < 2; ++t) {
        bf16x8 kf = *(const bf16x8*)&Kb_[(t * 32 + l31) * 64 +
                        ((hi5 ^ (l31 & 7)) * 8)];
        sacc[t] = __builtin_amdgcn_mfma_f32_32x32x16_bf16(kf, qf[0], cinit, 0, 0, 0);
      }
#pragma unroll
      for (int ks16 = 1; ks16 < 4; ++ks16) {
#pragma unroll
        for (int t = 0; t < 2; ++t) {
          bf16x8 kf = *(const bf16x8*)&Kb_[(t * 32 + l31) * 64 +
                          (((ks16 * 2 + hi5) ^ (l31 & 7)) * 8)];
          sacc[t] = __builtin_amdgcn_mfma_f32_32x32x16_bf16(kf, qf[ks16], sacc[t], 0, 0, 0);
        }
      }
      __builtin_amdgcn_s_setprio(0);
      asm volatile("" : "+v"(sacc[0]), "+v"(sacc[1]));

#pragma unroll
      for (int t = 0; t < 2; ++t)
#pragma unroll
        for (int r = 0; r < 16; ++r)
          sacc[t][r] = __builtin_amdgcn_exp2f(sacc[t][r]);
#pragma unroll
      for (int r = 0; r < 8; ++r)
        l8[r] += (sacc[0][r] + sacc[0][r + 8]) + (sacc[1][r] + sacc[1][r + 8]);

      uint32_t wpk[16];
#pragma unroll
      for (int t = 0; t < 2; ++t) {
        union { __bf16 hh[16]; uint32_t u[8]; } pk;
#pragma unroll
        for (int r = 0; r < 16; ++r) pk.hh[r] = (__bf16)sacc[t][r];
#pragma unroll
        for (int j = 0; j < 8; ++j) wpk[t * 8 + j] = pk.u[j];
      }
      uint32_t xw[8];
#pragma unroll
      for (int t = 0; t < 2; ++t) {
        xw[t * 4 + 0] = __shfl_xor(hi5 ? wpk[t * 8 + 0] : wpk[t * 8 + 2], 32);
        xw[t * 4 + 1] = __shfl_xor(hi5 ? wpk[t * 8 + 1] : wpk[t * 8 + 3], 32);
        xw[t * 4 + 2] = __shfl_xor(hi5 ? wpk[t * 8 + 4] : wpk[t * 8 + 6], 32);
        xw[t * 4 + 3] = __shfl_xor(hi5 ? wpk[t * 8 + 5] : wpk[t * 8 + 7], 32);
      }

      __builtin_amdgcn_s_setprio(1);
#pragma unroll
      for (int ks = 0; ks < 4; ++ks) {
        const int t = ks >> 1, b = (ks & 1) * 4, o = t * 8, xb = t * 4 + (ks & 1) * 2;
        union { uint32_t u[4]; bf16x8 v; } pu;
        pu.u[0] = hi5 ? xw[xb] : wpk[o + b];
        pu.u[1] = hi5 ? xw[xb + 1] : wpk[o + b + 1];
        pu.u[2] = hi5 ? wpk[o + b + 2] : xw[xb];
        pu.u[3] = hi5 ? wpk[o + b + 3] : xw[xb + 1];
#pragma unroll
        for (int dt = 0; dt < 2; ++dt) {
          bf16x8 vf = *(const bf16x8*)&Vb_[(dt * 32 + l31) * 64 +
                          (((ks * 2 + hi5) ^ (l31 & 7)) * 8)];
          oacc[dt] = __builtin_amdgcn_mfma_f32_32x32x16_bf16(vf, pu.v, oacc[dt], 0, 0, 0);
        }
      }
      __builtin_amdgcn_s_setprio(0);
    }
    __syncthreads();
  }

  float l = ((l8[0] + l8[4]) + (l8[1] + l8[5])) +
            ((l8[2] + l8[6]) + (l8[3] + l8[7]));
  l += __shfl_xor(l, 32);

  const float il = 1.0f / l;
  unsigned short* bw = &Ks[0][0] + w * 2048;
#pragma unroll
  for (int dt = 0; dt < 2; ++dt)
#pragma unroll
    for (int j = 0; j < 8; ++j) {
      const int dl = (j & 1) * 2 + (j >> 1) * 8 + hi5 * 4;
      const int d = dt * 32 + dl;
      const uint32_t pk = (uint32_t)f2bf(oacc[dt][2 * j] * il) |
                          ((uint32_t)f2bf(oacc[dt][2 * j + 1] * il) << 16);
      const int g = d >> 3, gi = (d >> 1) & 3;
      *(uint32_t*)&bw[l31 * 64 + ((g ^ (l31 & 7)) * 8) + gi * 2] = pk;
    }
  __syncthreads();
  const int bb = bh >> 4, hd = bh & 15;
#pragma unroll
  for (int i = 0; i < 4; ++i) {
    const int row = i * 8 + (lane >> 3);
    const int g = lane & 7;
    bf16x8 vv = *(const bf16x8*)&bw[row * 64 + ((g ^ (row & 7)) * 8)];
    *(bf16x8*)&At[((size_t)bb * TT + q0 + row) * CC + hd * DH + g * 8] = vv;
  }
}

extern "C" void kernel_launch(void* const* d_in, const int* in_sizes, int n_in,
                              void* d_out, int out_size, void* d_ws, size_t ws_size,
                              hipStream_t stream) {
  const float* x = (const float*)d_in[0];
  const float* Wqkv = (const float*)d_in[1];
  const float* bqkv = (const float*)d_in[2];
  const float* Wout = (const float*)d_in[3];
  const float* bout = (const float*)d_in[4];
  float* out = (float*)d_out;

  char* ws = (char*)d_ws;
  unsigned short* Xb  = (unsigned short*)(ws);                      // 16 MB
  unsigned short* WqT = (unsigned short*)(ws + (16ull << 20));      // 6 MB
  unsigned short* WoT = (unsigned short*)(ws + (22ull << 20));      // 2 MB
  unsigned short* Qb  = (unsigned short*)(ws + (24ull << 20));      // 16 MB
  unsigned short* Kb  = (unsigned short*)(ws + (40ull << 20));      // 16 MB
  unsigned short* Vt  = (unsigned short*)(ws + (56ull << 20));      // 16 MB
  unsigned short* At  = (unsigned short*)(ws + (72ull << 20));      // 16 MB (88 total)

  k_cvt<<<dim3((MM * KK) / (256 * 8)), 256, 0, stream>>>(x, Xb);
  k_tcvt<<<dim3(N1 / 32, KK / 32), 256, 0, stream>>>(Wqkv, WqT, KK, N1);
  k_tcvt<<<dim3(CC / 32, KK / 32), 256, 0, stream>>>(Wout, WoT, KK, CC);
  k_gemm4<0, 24><<<dim3((MM / 256) * (N1 / 128)), 512, 0, stream>>>(
      Xb, WqT, bqkv, MM, N1, KK, Qb, Kb, Vt, nullptr);
  k_attn<<<dim3(BB * HH * (TT / 128)), 256, 0, stream>>>(Qb, Kb, Vt, At, -16.0f);
  k_gemm4<1, 8><<<dim3((MM / 256) * (CC / 128)), 512, 0, stream>>>(
      At, WoT, bout, MM, CC, KK, nullptr, nullptr, nullptr, out);
}

// Round 15
// 199.828 us; speedup vs baseline: 1.0718x; 1.0718x over previous
//
#include <hip/hip_runtime.h>
#include <stdint.h>

typedef __bf16 bf16x8 __attribute__((ext_vector_type(8)));
typedef float f32x4 __attribute__((ext_vector_type(4)));
typedef float f32x16 __attribute__((ext_vector_type(16)));

static constexpr int BB = 4, TT = 2048, CC = 1024, HH = 16, DH = 64;
static constexpr int MM = BB * TT;   // 8192
static constexpr int N1 = 3 * CC;    // 3072
static constexpr int KK = CC;        // 1024

__device__ __forceinline__ unsigned short f2bf(float f) {
  uint32_t u = __builtin_bit_cast(uint32_t, f);
  u += 0x7FFFu + ((u >> 16) & 1u);
  return (unsigned short)(u >> 16);
}

__device__ __forceinline__ void async16(const void* g, void* l) {
  __builtin_amdgcn_global_load_lds((const __attribute__((address_space(1))) void*)g,
                                   (__attribute__((address_space(3))) void*)l, 16, 0, 0);
}

// ---- f32 -> bf16, 8 elems/thread ----
__global__ __launch_bounds__(256) void k_cvt(const float* __restrict__ src,
                                             unsigned short* __restrict__ dst) {
  int i = blockIdx.x * 256 + threadIdx.x;
  const float4* s = (const float4*)src + (size_t)i * 2;
  float4 a = s[0], b = s[1];
  union { unsigned short h[8]; uint4 v; } o;
  o.h[0] = f2bf(a.x); o.h[1] = f2bf(a.y); o.h[2] = f2bf(a.z); o.h[3] = f2bf(a.w);
  o.h[4] = f2bf(b.x); o.h[5] = f2bf(b.y); o.h[6] = f2bf(b.z); o.h[7] = f2bf(b.w);
  ((uint4*)dst)[i] = o.v;
}

// ---- transpose + convert: src[R][C] f32 -> dst[C][R] bf16 ----
__global__ __launch_bounds__(256) void k_tcvt(const float* __restrict__ src,
                                              unsigned short* __restrict__ dst,
                                              int R, int C) {
  __shared__ float tile[32][33];
  int tx = threadIdx.x & 31, ty = threadIdx.x >> 5;
  int c0 = blockIdx.x * 32, r0 = blockIdx.y * 32;
#pragma unroll
  for (int i = 0; i < 4; ++i)
    tile[ty + i * 8][tx] = src[(size_t)(r0 + ty + i * 8) * C + c0 + tx];
  __syncthreads();
#pragma unroll
  for (int i = 0; i < 4; ++i)
    dst[(size_t)(c0 + ty + i * 8) * R + r0 + tx] = f2bf(tile[tx][ty + i * 8]);
}

// ============ 256x128 4-phase GEMM (T1+T2+T3+T4+T5), 96KB LDS ============
#define LDA4(Ab, mf, ksl) \
  (*(const bf16x8*)&(Ab)[(wm * 128 + (mf) * 16 + l15) * 64 + \
                         ((((ksl) * 4 + l16) ^ (l15 & 7)) * 8)])
#define LDB4(Bb, nf, ksl) \
  (*(const bf16x8*)&(Bb)[(wn * 32 + (nf) * 16 + l15) * 64 + \
                         ((((ksl) * 4 + l16) ^ (l15 & 7)) * 8)])

struct AF8 { bf16x8 a[8]; };

template <int P, bool LOADB>
__device__ __forceinline__ AF8 phase_pre4(const unsigned short* Ab, const unsigned short* Bb,
                                          int wm, int wn, int l15, int l16, bf16x8* bfr) {
  AF8 f;
#pragma unroll
  for (int mf = 0; mf < 4; ++mf) {
    f.a[mf * 2] = LDA4(Ab, P * 4 + mf, 0);
    f.a[mf * 2 + 1] = LDA4(Ab, P * 4 + mf, 1);
  }
  if (LOADB) {
#pragma unroll
    for (int nf = 0; nf < 2; ++nf) {
      bfr[nf * 2] = LDB4(Bb, nf, 0);
      bfr[nf * 2 + 1] = LDB4(Bb, nf, 1);
    }
  }
  return f;
}

template <int P>
__device__ __forceinline__ void phase_mfma4(const AF8& f, const bf16x8* bfr, f32x4 acc[8][2]) {
#pragma unroll
  for (int mf = 0; mf < 4; ++mf)
#pragma unroll
    for (int nf = 0; nf < 2; ++nf) {
      acc[P * 4 + mf][nf] = __builtin_amdgcn_mfma_f32_16x16x32_bf16(
          f.a[mf * 2], bfr[nf * 2], acc[P * 4 + mf][nf], 0, 0, 0);
      acc[P * 4 + mf][nf] = __builtin_amdgcn_mfma_f32_16x16x32_bf16(
          f.a[mf * 2 + 1], bfr[nf * 2 + 1], acc[P * 4 + mf][nf], 0, 0, 0);
    }
}

#define PHASE4(P, AB, BB_, LOADB, STAGES, WAITS)                      \
  { AF8 f_ = phase_pre4<P, LOADB>(AB, BB_, wm, wn, l15, l16, bfr);    \
    STAGES;                                                           \
    WAITS;                                                            \
    __builtin_amdgcn_s_barrier();                                     \
    asm volatile("s_waitcnt lgkmcnt(0)" ::: "memory");                \
    __builtin_amdgcn_sched_barrier(0);                                \
    __builtin_amdgcn_s_setprio(1);                                    \
    phase_mfma4<P>(f_, bfr, acc);                                     \
    __builtin_amdgcn_s_setprio(0);                                    \
    __builtin_amdgcn_s_barrier(); }

template <int MODE, int NBX>
__global__ __launch_bounds__(512, 2) void k_gemm4(
    const unsigned short* __restrict__ A, const unsigned short* __restrict__ Bt,
    const float* __restrict__ bias, int M, int N, int K,
    unsigned short* __restrict__ qo, unsigned short* __restrict__ ko,
    unsigned short* __restrict__ vo, float* __restrict__ fo) {
  __shared__ __attribute__((aligned(16))) unsigned short lds[49152];  // 96 KB
  unsigned short* As0 = lds;           // [256][64]
  unsigned short* As1 = lds + 16384;
  unsigned short* Bs0 = lds + 32768;   // [128][64]
  unsigned short* Bs1 = lds + 40960;

  const int tid = threadIdx.x;
  const int lane = tid & 63;
  const int w = tid >> 6, wm = w >> 2, wn = w & 3;
  const int l15 = lane & 15, l16 = lane >> 4;

  const int q8 = (int)gridDim.x >> 3;
  const int swz = ((int)blockIdx.x & 7) * q8 + ((int)blockIdx.x >> 3);
  const int m0 = (swz / NBX) * 256, n0 = (swz % NBX) * 128;

  f32x4 acc[8][2] = {};

  const int srow = tid >> 3;                       // 0..63
  const int sg = ((tid & 7) ^ (srow & 7)) * 8;
  const int dOff = srow * 64 + (tid & 7) * 8;
  const unsigned short* aBase = A + (size_t)(m0 + srow) * K + sg;
  const unsigned short* bBase = Bt + (size_t)(n0 + srow) * K + sg;

#define STAGE_A(dst, kt, h)                                                          \
  { async16(aBase + (size_t)((h) * 128) * K + (kt) * 64, (dst) + (h) * 8192 + dOff); \
    async16(aBase + (size_t)((h) * 128 + 64) * K + (kt) * 64,                        \
            (dst) + (h) * 8192 + 4096 + dOff); }
#define STAGE_B(dst, kt)                                                             \
  { async16(bBase + (kt) * 64, (dst) + dOff);                                        \
    async16(bBase + (size_t)64 * K + (kt) * 64, (dst) + 4096 + dOff); }

  STAGE_A(As0, 0, 0); STAGE_A(As0, 0, 1);
  STAGE_B(Bs0, 0);
  STAGE_B(Bs1, 1);
  asm volatile("s_waitcnt vmcnt(0)" ::: "memory");
  __builtin_amdgcn_s_barrier();

  const int NITER = K / 128;
#pragma unroll 1
  for (int i = 0; i < NITER; ++i) {
    const bool more = (i + 1 < NITER);
    const int tb = 2 * i + 1, t2k = 2 * i + 2, t3 = 2 * i + 3;
    bf16x8 bfr[4];
    PHASE4(0, As0, Bs0, true,
           { STAGE_A(As1, tb, 0); STAGE_A(As1, tb, 1); }, ((void)0));
    PHASE4(1, As0, Bs0, false,
           { if (more) STAGE_B(Bs0, t2k); },
           { if (more) { asm volatile("s_waitcnt vmcnt(2)" ::: "memory"); }
             else      { asm volatile("s_waitcnt vmcnt(0)" ::: "memory"); } });
    PHASE4(0, As1, Bs1, true,
           { if (more) { STAGE_A(As0, t2k, 0); STAGE_A(As0, t2k, 1); } }, ((void)0));
    PHASE4(1, As1, Bs1, false,
           { if (more) STAGE_B(Bs1, t3); },
           { if (more) { asm volatile("s_waitcnt vmcnt(2)" ::: "memory"); } });
  }

  // ---- epilogue ----
  if (MODE == 0) {
    const int sel = n0 >> 10;
    if (sel < 2) {
      const float qs = (sel == 0) ? 0.180336892f : 1.0f;
      float bj[2];
#pragma unroll
      for (int nf = 0; nf < 2; ++nf) bj[nf] = bias[n0 + wn * 32 + nf * 16 + l15];
#pragma unroll
      for (int mf = 0; mf < 8; ++mf)
#pragma unroll
        for (int nf = 0; nf < 2; ++nf)
#pragma unroll
          for (int r = 0; r < 4; ++r) {
            const int row = wm * 128 + mf * 16 + l16 * 4 + r;
            const int col = wn * 32 + nf * 16 + l15;
            lds[row * 128 + (col >> 6) * 64 +
                ((((col >> 3) & 7) ^ (row & 7)) * 8) + (col & 7)] =
                f2bf((acc[mf][nf][r] + bj[nf]) * qs);
          }
      __syncthreads();
      const int row = tid >> 1, half = tid & 1;
      const int gm = m0 + row, bb2 = gm >> 11, t2 = gm & 2047;
      const int h2 = ((n0 & 1023) >> 6) + half;
      unsigned short* dst = (sel == 0 ? qo : ko) +
          ((size_t)(bb2 * HH + h2) * TT + t2) * DH;
#pragma unroll
      for (int g = 0; g < 8; ++g) {
        bf16x8 v = *(const bf16x8*)&lds[row * 128 + half * 64 + ((g ^ (row & 7)) * 8)];
        *(bf16x8*)&dst[g * 8] = v;
      }
    } else {
#pragma unroll
      for (int mf = 0; mf < 8; ++mf)
#pragma unroll
        for (int nf = 0; nf < 2; ++nf) {
          const int gn = n0 + wn * 32 + nf * 16 + l15;
          const float bj = bias[gn];
          const int h = (gn & 1023) >> 6, d = gn & 63;
          const int gm0 = m0 + wm * 128 + mf * 16 + l16 * 4;
          const int bb2 = gm0 >> 11, t0 = gm0 & 2047;
          union { unsigned short s[4]; uint2 u; } pk;
#pragma unroll
          for (int r = 0; r < 4; ++r) pk.s[r] = f2bf(acc[mf][nf][r] + bj);
          *(uint2*)&vo[((size_t)(bb2 * HH + h) * DH + d) * TT + t0] = pk.u;
        }
    }
  } else {
#pragma unroll
    for (int mf = 0; mf < 8; ++mf)
#pragma unroll
      for (int nf = 0; nf < 2; ++nf) {
        const int gn = n0 + wn * 32 + nf * 16 + l15;
        const float bj = bias[gn];
#pragma unroll
        for (int r = 0; r < 4; ++r) {
          const int gm = m0 + wm * 128 + mf * 16 + l16 * 4 + r;
          fo[(size_t)gm * N + gn] = acc[mf][nf][r] + bj;
        }
      }
  }
#undef STAGE_A
#undef STAGE_B
}

// ---- flash attention, swapped-QK^T 32x32, fixed-max softmax (r10 best) ----
__global__ __launch_bounds__(256, 2) void k_attn(
    const unsigned short* __restrict__ Q,   // [64][T][64] bh-major, scale=0.125*log2e
    const unsigned short* __restrict__ Kx,  // [64][T][64]
    const unsigned short* __restrict__ Vt,  // [64][64][T]  (d-major)
    unsigned short* __restrict__ At,        // [B][T][C]
    float neg16) {
  __shared__ __attribute__((aligned(16))) unsigned short Ks[2][64 * 64];
  __shared__ __attribute__((aligned(16))) unsigned short Vs[2][64 * 64];
  const int tid = threadIdx.x, lane = tid & 63, w = tid >> 6;
  const int l31 = lane & 31, hi5 = lane >> 5;
  const int id = blockIdx.x;
  const int bh = (id & 7) + ((id >> 7) << 3);
  const int qb = (id >> 3) & 15;
  const int q0 = qb * 128 + w * 32;
  const unsigned short* Qp = Q + (size_t)bh * TT * DH;
  const unsigned short* Kp = Kx + (size_t)bh * TT * DH;
  const unsigned short* Vp = Vt + (size_t)bh * DH * TT;

  bf16x8 qf[4];
#pragma unroll
  for (int j = 0; j < 4; ++j)
    qf[j] = *(const bf16x8*)&Qp[(size_t)(q0 + l31) * DH + j * 16 + hi5 * 8];

  f32x16 cinit;
#pragma unroll
  for (int r = 0; r < 16; ++r) cinit[r] = neg16;

  const int srow = tid >> 3;
  const int sg = ((tid & 7) ^ (srow & 7)) * 8;

  float l8[8];
#pragma unroll
  for (int r = 0; r < 8; ++r) l8[r] = 0.f;
  f32x16 oacc[2] = {};

#pragma unroll
  for (int i = 0; i < 2; ++i) {
    async16(Kp + (size_t)(i * 32 + srow) * DH + sg, &Ks[0][i * 2048 + tid * 8]);
    async16(Vp + (size_t)(i * 32 + srow) * TT + sg, &Vs[0][i * 2048 + tid * 8]);
  }
  __syncthreads();

#pragma unroll 2
  for (int kt = 0; kt < TT / 64; ++kt) {
    const int cur = kt & 1;
    if (kt + 1 < TT / 64) {
      const int kv1 = (kt + 1) * 64;
#pragma unroll
      for (int i = 0; i < 2; ++i) {
        async16(Kp + (size_t)(kv1 + i * 32 + srow) * DH + sg,
                &Ks[cur ^ 1][i * 2048 + tid * 8]);
        async16(Vp + (size_t)(i * 32 + srow) * TT + kv1 + sg,
                &Vs[cur ^ 1][i * 2048 + tid * 8]);
      }
    }

    f32x16 sacc[2];
    __builtin_amdgcn_s_setprio(1);
#pragma unroll
    for (int t = 0; t < 2; ++t) {
      bf16x8 kf = *(const bf16x8*)&Ks[cur][(t * 32 + l31) * 64 +
                      ((hi5 ^ (l31 & 7)) * 8)];
      sacc[t] = __builtin_amdgcn_mfma_f32_32x32x16_bf16(kf, qf[0], cinit, 0, 0, 0);
    }
#pragma unroll
    for (int ks16 = 1; ks16 < 4; ++ks16) {
#pragma unroll
      for (int t = 0; t < 2; ++t) {
        bf16x8 kf = *(const bf16x8*)&Ks[cur][(t * 32 + l31) * 64 +
                        (((ks16 * 2 + hi5) ^ (l31 & 7)) * 8)];
        sacc[t] = __builtin_amdgcn_mfma_f32_32x32x16_bf16(kf, qf[ks16], sacc[t], 0, 0, 0);
      }
    }
    __builtin_amdgcn_s_setprio(0);
    asm volatile("" : "+v"(sacc[0]), "+v"(sacc[1]));

#pragma unroll
    for (int t = 0; t < 2; ++t)
#pragma unroll
      for (int r = 0; r < 16; ++r)
        sacc[t][r] = __builtin_amdgcn_exp2f(sacc[t][r]);
#pragma unroll
    for (int r = 0; r < 4; ++r)
      l8[r] += (sacc[0][r] + sacc[0][r + 8]) + (sacc[1][r] + sacc[1][r + 8]);
#pragma unroll
    for (int r = 4; r < 8; ++r)
      l8[r] += (sacc[0][r] + sacc[0][r + 8]) + (sacc[1][r] + sacc[1][r + 8]);

    uint32_t wpk[16];
#pragma unroll
    for (int t = 0; t < 2; ++t) {
      union { __bf16 h[16]; uint32_t u[8]; } pk;
#pragma unroll
      for (int r = 0; r < 16; ++r) pk.h[r] = (__bf16)sacc[t][r];
#pragma unroll
      for (int j = 0; j < 8; ++j) wpk[t * 8 + j] = pk.u[j];
    }
    uint32_t xw[8];
#pragma unroll
    for (int t = 0; t < 2; ++t) {
      xw[t * 4 + 0] = __shfl_xor(hi5 ? wpk[t * 8 + 0] : wpk[t * 8 + 2], 32);
      xw[t * 4 + 1] = __shfl_xor(hi5 ? wpk[t * 8 + 1] : wpk[t * 8 + 3], 32);
      xw[t * 4 + 2] = __shfl_xor(hi5 ? wpk[t * 8 + 4] : wpk[t * 8 + 6], 32);
      xw[t * 4 + 3] = __shfl_xor(hi5 ? wpk[t * 8 + 5] : wpk[t * 8 + 7], 32);
    }

    __builtin_amdgcn_s_setprio(1);
#pragma unroll
    for (int ks = 0; ks < 4; ++ks) {
      const int t = ks >> 1, b = (ks & 1) * 4, o = t * 8, xb = t * 4 + (ks & 1) * 2;
      union { uint32_t u[4]; bf16x8 v; } pu;
      pu.u[0] = hi5 ? xw[xb] : wpk[o + b];
      pu.u[1] = hi5 ? xw[xb + 1] : wpk[o + b + 1];
      pu.u[2] = hi5 ? wpk[o + b + 2] : xw[xb];
      pu.u[3] = hi5 ? wpk[o + b + 3] : xw[xb + 1];
#pragma unroll
      for (int dt = 0; dt < 2; ++dt) {
        bf16x8 vf = *(const bf16x8*)&Vs[cur][(dt * 32 + l31) * 64 +
                        (((ks * 2 + hi5) ^ (l31 & 7)) * 8)];
        oacc[dt] = __builtin_amdgcn_mfma_f32_32x32x16_bf16(vf, pu.v, oacc[dt], 0, 0, 0);
      }
    }
    __builtin_amdgcn_s_setprio(0);
    __syncthreads();
  }

  float l = ((l8[0] + l8[4]) + (l8[1] + l8[5])) +
            ((l8[2] + l8[6]) + (l8[3] + l8[7]));
  l += __shfl_xor(l, 32);

  const float il = 1.0f / l;
  unsigned short* bw = &Ks[0][0] + w * 2048;
#pragma unroll
  for (int dt = 0; dt < 2; ++dt)
#pragma unroll
    for (int j = 0; j < 8; ++j) {
      const int dl = (j & 1) * 2 + (j >> 1) * 8 + hi5 * 4;
      const int d = dt * 32 + dl;
      const uint32_t pk = (uint32_t)f2bf(oacc[dt][2 * j] * il) |
                          ((uint32_t)f2bf(oacc[dt][2 * j + 1] * il) << 16);
      const int g = d >> 3, gi = (d >> 1) & 3;
      *(uint32_t*)&bw[l31 * 64 + ((g ^ (l31 & 7)) * 8) + gi * 2] = pk;
    }
  __syncthreads();
  const int bb = bh >> 4, hd = bh & 15;
#pragma unroll
  for (int i = 0; i < 4; ++i) {
    const int row = i * 8 + (lane >> 3);
    const int g = lane & 7;
    bf16x8 vv = *(const bf16x8*)&bw[row * 64 + ((g ^ (row & 7)) * 8)];
    *(bf16x8*)&At[((size_t)bb * TT + q0 + row) * CC + hd * DH + g * 8] = vv;
  }
}

extern "C" void kernel_launch(void* const* d_in, const int* in_sizes, int n_in,
                              void* d_out, int out_size, void* d_ws, size_t ws_size,
                              hipStream_t stream) {
  const float* x = (const float*)d_in[0];
  const float* Wqkv = (const float*)d_in[1];
  const float* bqkv = (const float*)d_in[2];
  const float* Wout = (const float*)d_in[3];
  const float* bout = (const float*)d_in[4];
  float* out = (float*)d_out;

  char* ws = (char*)d_ws;
  unsigned short* Xb  = (unsigned short*)(ws);                      // 16 MB
  unsigned short* WqT = (unsigned short*)(ws + (16ull << 20));      // 6 MB
  unsigned short* WoT = (unsigned short*)(ws + (22ull << 20));      // 2 MB
  unsigned short* Qb  = (unsigned short*)(ws + (24ull << 20));      // 16 MB
  unsigned short* Kb  = (unsigned short*)(ws + (40ull << 20));      // 16 MB
  unsigned short* Vt  = (unsigned short*)(ws + (56ull << 20));      // 16 MB
  unsigned short* At  = (unsigned short*)(ws + (72ull << 20));      // 16 MB (88 total)

  k_cvt<<<dim3((MM * KK) / (256 * 8)), 256, 0, stream>>>(x, Xb);
  k_tcvt<<<dim3(N1 / 32, KK / 32), 256, 0, stream>>>(Wqkv, WqT, KK, N1);
  k_tcvt<<<dim3(CC / 32, KK / 32), 256, 0, stream>>>(Wout, WoT, KK, CC);
  k_gemm4<0, 24><<<dim3((MM / 256) * (N1 / 128)), 512, 0, stream>>>(
      Xb, WqT, bqkv, MM, N1, KK, Qb, Kb, Vt, nullptr);
  k_attn<<<dim3(BB * HH * (TT / 128)), 256, 0, stream>>>(Qb, Kb, Vt, At, -16.0f);
  k_gemm4<1, 8><<<dim3((MM / 256) * (CC / 128)), 512, 0, stream>>>(
      At, WoT, bout, MM, CC, KK, nullptr, nullptr, nullptr, out);
}

// Round 17
// 187.246 us; speedup vs baseline: 1.1438x; 1.0672x over previous
//
#include <hip/hip_runtime.h>
#include <stdint.h>

typedef __bf16 bf16x8 __attribute__((ext_vector_type(8)));
typedef float f32x4 __attribute__((ext_vector_type(4)));
typedef float f32x16 __attribute__((ext_vector_type(16)));

static constexpr int BB = 4, TT = 2048, CC = 1024, HH = 16, DH = 64;
static constexpr int MM = BB * TT;   // 8192
static constexpr int N1 = 3 * CC;    // 3072
static constexpr int KK = CC;        // 1024

__device__ __forceinline__ unsigned short f2bf(float f) {
  uint32_t u = __builtin_bit_cast(uint32_t, f);
  u += 0x7FFFu + ((u >> 16) & 1u);
  return (unsigned short)(u >> 16);
}

__device__ __forceinline__ void async16(const void* g, void* l) {
  __builtin_amdgcn_global_load_lds((const __attribute__((address_space(1))) void*)g,
                                   (__attribute__((address_space(3))) void*)l, 16, 0, 0);
}

// ---- f32 -> bf16, 8 elems/thread ----
__global__ __launch_bounds__(256) void k_cvt(const float* __restrict__ src,
                                             unsigned short* __restrict__ dst) {
  int i = blockIdx.x * 256 + threadIdx.x;
  const float4* s = (const float4*)src + (size_t)i * 2;
  float4 a = s[0], b = s[1];
  union { unsigned short h[8]; uint4 v; } o;
  o.h[0] = f2bf(a.x); o.h[1] = f2bf(a.y); o.h[2] = f2bf(a.z); o.h[3] = f2bf(a.w);
  o.h[4] = f2bf(b.x); o.h[5] = f2bf(b.y); o.h[6] = f2bf(b.z); o.h[7] = f2bf(b.w);
  ((uint4*)dst)[i] = o.v;
}

// ---- transpose + convert: src[R][C] f32 -> dst[C][R] bf16 ----
__global__ __launch_bounds__(256) void k_tcvt(const float* __restrict__ src,
                                              unsigned short* __restrict__ dst,
                                              int R, int C) {
  __shared__ float tile[32][33];
  int tx = threadIdx.x & 31, ty = threadIdx.x >> 5;
  int c0 = blockIdx.x * 32, r0 = blockIdx.y * 32;
#pragma unroll
  for (int i = 0; i < 4; ++i)
    tile[ty + i * 8][tx] = src[(size_t)(r0 + ty + i * 8) * C + c0 + tx];
  __syncthreads();
#pragma unroll
  for (int i = 0; i < 4; ++i)
    dst[(size_t)(c0 + ty + i * 8) * R + r0 + tx] = f2bf(tile[tx][ty + i * 8]);
}

// ===== 128x128 4-phase GEMM (T1+T2+T3+T4+T5), 64KB LDS -> 2 blocks/CU =====
// 256 thr = 4 waves (2x2), per-wave 64x64 (acc[4][4]). Iter i: tiles a=2i
// (buf0), b=2i+1 (buf1), 2 phases each, 16 MFMA/phase; B-frags reg-resident
// per tile. Stage slots (4 loads ea): ph1 A(2i+1) | ph2 B(2i+2)+vmcnt(4) |
// ph3 A(2i+2) | ph4 B(2i+3)+vmcnt(4); last iter ph2 -> vmcnt(0).
// STAGING OBEYS the global_load_lds invariant (rule #21/m104): per call,
// LDS dst = base + tid*8 elems = wave-uniform + lane*16B; 4 calls cover
// rows i*32+srow (i=0..3), swizzle preserved since 32 % 8 == 0.

#define LDA2(Ab, mf, ksl) \
  (*(const bf16x8*)&(Ab)[(wm * 64 + (mf) * 16 + l15) * 64 + \
                         ((((ksl) * 4 + l16) ^ (l15 & 7)) * 8)])
#define LDB2(Bb, nf, ksl) \
  (*(const bf16x8*)&(Bb)[(wn * 64 + (nf) * 16 + l15) * 64 + \
                         ((((ksl) * 4 + l16) ^ (l15 & 7)) * 8)])

struct AF4g { bf16x8 a00, a01, a10, a11; };

template <int P, bool LOADB>
__device__ __forceinline__ AF4g phase_pre2(const unsigned short* Ab, const unsigned short* Bb,
                                           int wm, int wn, int l15, int l16, bf16x8* bfr) {
  AF4g f;
  f.a00 = LDA2(Ab, P * 2, 0);     f.a01 = LDA2(Ab, P * 2, 1);
  f.a10 = LDA2(Ab, P * 2 + 1, 0); f.a11 = LDA2(Ab, P * 2 + 1, 1);
  if (LOADB) {
#pragma unroll
    for (int nf = 0; nf < 4; ++nf) {
      bfr[nf] = LDB2(Bb, nf, 0);
      bfr[4 + nf] = LDB2(Bb, nf, 1);
    }
  }
  return f;
}

template <int P>
__device__ __forceinline__ void phase_mfma2(const AF4g& f, const bf16x8* bfr, f32x4 acc[4][4]) {
#pragma unroll
  for (int nf = 0; nf < 4; ++nf)
    acc[P * 2][nf] = __builtin_amdgcn_mfma_f32_16x16x32_bf16(f.a00, bfr[nf], acc[P * 2][nf], 0, 0, 0);
#pragma unroll
  for (int nf = 0; nf < 4; ++nf)
    acc[P * 2][nf] = __builtin_amdgcn_mfma_f32_16x16x32_bf16(f.a01, bfr[4 + nf], acc[P * 2][nf], 0, 0, 0);
#pragma unroll
  for (int nf = 0; nf < 4; ++nf)
    acc[P * 2 + 1][nf] = __builtin_amdgcn_mfma_f32_16x16x32_bf16(f.a10, bfr[nf], acc[P * 2 + 1][nf], 0, 0, 0);
#pragma unroll
  for (int nf = 0; nf < 4; ++nf)
    acc[P * 2 + 1][nf] = __builtin_amdgcn_mfma_f32_16x16x32_bf16(f.a11, bfr[4 + nf], acc[P * 2 + 1][nf], 0, 0, 0);
}

#define PHASE2(P, AB, BB_, LOADB, STAGES, WAITS)                      \
  { AF4g f_ = phase_pre2<P, LOADB>(AB, BB_, wm, wn, l15, l16, bfr);   \
    STAGES;                                                           \
    WAITS;                                                            \
    __builtin_amdgcn_s_barrier();                                     \
    asm volatile("s_waitcnt lgkmcnt(0)" ::: "memory");                \
    __builtin_amdgcn_sched_barrier(0);                                \
    __builtin_amdgcn_s_setprio(1);                                    \
    phase_mfma2<P>(f_, bfr, acc);                                     \
    __builtin_amdgcn_s_setprio(0);                                    \
    __builtin_amdgcn_s_barrier(); }

template <int MODE, int NBX>
__global__ __launch_bounds__(256, 2) void k_gemm2t(
    const unsigned short* __restrict__ A, const unsigned short* __restrict__ Bt,
    const float* __restrict__ bias, int M, int N, int K,
    unsigned short* __restrict__ qo, unsigned short* __restrict__ ko,
    unsigned short* __restrict__ vo, float* __restrict__ fo) {
  __shared__ __attribute__((aligned(16))) unsigned short lds[32768];  // 64 KB
  unsigned short* As0 = lds;            // [128][64]
  unsigned short* As1 = lds + 8192;
  unsigned short* Bs0 = lds + 16384;    // [128][64]
  unsigned short* Bs1 = lds + 24576;

  const int tid = threadIdx.x;
  const int lane = tid & 63;
  const int w = tid >> 6, wm = w >> 1, wn = w & 1;
  const int l15 = lane & 15, l16 = lane >> 4;

  // bijective XCD swizzle (gridDim.x % 8 == 0); n-fastest within XCD chunk
  const int q8 = (int)gridDim.x >> 3;
  const int swz = ((int)blockIdx.x & 7) * q8 + ((int)blockIdx.x >> 3);
  const int m0 = (swz / NBX) * 128, n0 = (swz % NBX) * 128;

  f32x4 acc[4][4] = {};

  // staging (lane*16B invariant): srow = tid>>3 (0..31), 4 calls cover
  // rows i*32+srow; pre-swizzled global col; dst = buf + i*2048 + tid*8.
  const int srow = tid >> 3;
  const int sg = ((tid & 7) ^ (srow & 7)) * 8;
  const unsigned short* aBase = A + (size_t)(m0 + srow) * K + sg;
  const unsigned short* bBase = Bt + (size_t)(n0 + srow) * K + sg;

#define STAGE_A(dst, kt)                                                        \
  { async16(aBase + (size_t)0 * K + (kt) * 64, (dst) + 0 * 2048 + tid * 8);     \
    async16(aBase + (size_t)32 * K + (kt) * 64, (dst) + 1 * 2048 + tid * 8);    \
    async16(aBase + (size_t)64 * K + (kt) * 64, (dst) + 2 * 2048 + tid * 8);    \
    async16(aBase + (size_t)96 * K + (kt) * 64, (dst) + 3 * 2048 + tid * 8); }
#define STAGE_B(dst, kt)                                                        \
  { async16(bBase + (size_t)0 * K + (kt) * 64, (dst) + 0 * 2048 + tid * 8);     \
    async16(bBase + (size_t)32 * K + (kt) * 64, (dst) + 1 * 2048 + tid * 8);    \
    async16(bBase + (size_t)64 * K + (kt) * 64, (dst) + 2 * 2048 + tid * 8);    \
    async16(bBase + (size_t)96 * K + (kt) * 64, (dst) + 3 * 2048 + tid * 8); }

  // prologue: A(0),B(0) -> buf0; B(1) -> buf1. A(1) staged in iter0 ph1.
  STAGE_A(As0, 0);
  STAGE_B(Bs0, 0);
  STAGE_B(Bs1, 1);
  asm volatile("s_waitcnt vmcnt(0)" ::: "memory");
  __builtin_amdgcn_s_barrier();

  const int NITER = K / 128;
#pragma unroll 1
  for (int i = 0; i < NITER; ++i) {
    const bool more = (i + 1 < NITER);
    const int tb = 2 * i + 1, t2k = 2 * i + 2, t3 = 2 * i + 3;
    bf16x8 bfr[8];
    PHASE2(0, As0, Bs0, true,  { STAGE_A(As1, tb); }, ((void)0));
    PHASE2(1, As0, Bs0, false,
           { if (more) STAGE_B(Bs0, t2k); },
           { if (more) { asm volatile("s_waitcnt vmcnt(4)" ::: "memory"); }
             else      { asm volatile("s_waitcnt vmcnt(0)" ::: "memory"); } });
    PHASE2(0, As1, Bs1, true,  { if (more) STAGE_A(As0, t2k); }, ((void)0));
    PHASE2(1, As1, Bs1, false,
           { if (more) STAGE_B(Bs1, t3); },
           { if (more) { asm volatile("s_waitcnt vmcnt(4)" ::: "memory"); } });
  }

  // ---- epilogue ----
  if (MODE == 0) {
    const int sel = n0 >> 10;   // 128-col block never straddles Q/K/V
    if (sel < 2) {
      // Q/K: bounce through LDS ([128][128] bf16 = 32KB), coalesced 16B stores
      const float qs = (sel == 0) ? 0.180336892f : 1.0f;
      float bj[4];
#pragma unroll
      for (int nf = 0; nf < 4; ++nf) bj[nf] = bias[n0 + wn * 64 + nf * 16 + l15];
#pragma unroll
      for (int mf = 0; mf < 4; ++mf)
#pragma unroll
        for (int nf = 0; nf < 4; ++nf)
#pragma unroll
          for (int r = 0; r < 4; ++r) {
            const int row = wm * 64 + mf * 16 + l16 * 4 + r;
            const int col = wn * 64 + nf * 16 + l15;
            lds[row * 128 + (col >> 6) * 64 +
                ((((col >> 3) & 7) ^ (row & 7)) * 8) + (col & 7)] =
                f2bf((acc[mf][nf][r] + bj[nf]) * qs);
          }
      __syncthreads();
      const int row = tid >> 1, half = tid & 1;
      const int gm = m0 + row, bb2 = gm >> 11, t2 = gm & 2047;
      const int h2 = ((n0 & 1023) >> 6) + half;
      unsigned short* dst = (sel == 0 ? qo : ko) +
          ((size_t)(bb2 * HH + h2) * TT + t2) * DH;
#pragma unroll
      for (int g = 0; g < 8; ++g) {
        bf16x8 v = *(const bf16x8*)&lds[row * 128 + half * 64 + ((g ^ (row & 7)) * 8)];
        *(bf16x8*)&dst[g * 8] = v;
      }
    } else {
      // V^T: r-quad packed 8B stores
#pragma unroll
      for (int mf = 0; mf < 4; ++mf)
#pragma unroll
        for (int nf = 0; nf < 4; ++nf) {
          const int gn = n0 + wn * 64 + nf * 16 + l15;
          const float bj = bias[gn];
          const int h = (gn & 1023) >> 6, d = gn & 63;
          const int gm0 = m0 + wm * 64 + mf * 16 + l16 * 4;
          const int bb2 = gm0 >> 11, t0 = gm0 & 2047;
          union { unsigned short s[4]; uint2 u; } pk;
#pragma unroll
          for (int r = 0; r < 4; ++r) pk.s[r] = f2bf(acc[mf][nf][r] + bj);
          *(uint2*)&vo[((size_t)(bb2 * HH + h) * DH + d) * TT + t0] = pk.u;
        }
    }
  } else {
#pragma unroll
    for (int mf = 0; mf < 4; ++mf)
#pragma unroll
      for (int nf = 0; nf < 4; ++nf) {
        const int gn = n0 + wn * 64 + nf * 16 + l15;
        const float bj = bias[gn];
#pragma unroll
        for (int r = 0; r < 4; ++r) {
          const int gm = m0 + wm * 64 + mf * 16 + l16 * 4 + r;
          fo[(size_t)gm * N + gn] = acc[mf][nf][r] + bj;
        }
      }
  }
#undef STAGE_A
#undef STAGE_B
}

// ---- flash attention, swapped-QK^T 32x32, fixed-max softmax (r10/r15 best) ----
__global__ __launch_bounds__(256, 2) void k_attn(
    const unsigned short* __restrict__ Q,   // [64][T][64] bh-major, scale=0.125*log2e
    const unsigned short* __restrict__ Kx,  // [64][T][64]
    const unsigned short* __restrict__ Vt,  // [64][64][T]  (d-major)
    unsigned short* __restrict__ At,        // [B][T][C]
    float neg16) {
  __shared__ __attribute__((aligned(16))) unsigned short Ks[2][64 * 64];
  __shared__ __attribute__((aligned(16))) unsigned short Vs[2][64 * 64];
  const int tid = threadIdx.x, lane = tid & 63, w = tid >> 6;
  const int l31 = lane & 31, hi5 = lane >> 5;
  const int id = blockIdx.x;
  const int bh = (id & 7) + ((id >> 7) << 3);
  const int qb = (id >> 3) & 15;
  const int q0 = qb * 128 + w * 32;
  const unsigned short* Qp = Q + (size_t)bh * TT * DH;
  const unsigned short* Kp = Kx + (size_t)bh * TT * DH;
  const unsigned short* Vp = Vt + (size_t)bh * DH * TT;

  bf16x8 qf[4];
#pragma unroll
  for (int j = 0; j < 4; ++j)
    qf[j] = *(const bf16x8*)&Qp[(size_t)(q0 + l31) * DH + j * 16 + hi5 * 8];

  f32x16 cinit;
#pragma unroll
  for (int r = 0; r < 16; ++r) cinit[r] = neg16;

  const int srow = tid >> 3;
  const int sg = ((tid & 7) ^ (srow & 7)) * 8;

  float l8[8];
#pragma unroll
  for (int r = 0; r < 8; ++r) l8[r] = 0.f;
  f32x16 oacc[2] = {};

#pragma unroll
  for (int i = 0; i < 2; ++i) {
    async16(Kp + (size_t)(i * 32 + srow) * DH + sg, &Ks[0][i * 2048 + tid * 8]);
    async16(Vp + (size_t)(i * 32 + srow) * TT + sg, &Vs[0][i * 2048 + tid * 8]);
  }
  __syncthreads();

#pragma unroll 2
  for (int kt = 0; kt < TT / 64; ++kt) {
    const int cur = kt & 1;
    if (kt + 1 < TT / 64) {
      const int kv1 = (kt + 1) * 64;
#pragma unroll
      for (int i = 0; i < 2; ++i) {
        async16(Kp + (size_t)(kv1 + i * 32 + srow) * DH + sg,
                &Ks[cur ^ 1][i * 2048 + tid * 8]);
        async16(Vp + (size_t)(i * 32 + srow) * TT + kv1 + sg,
                &Vs[cur ^ 1][i * 2048 + tid * 8]);
      }
    }

    f32x16 sacc[2];
    __builtin_amdgcn_s_setprio(1);
#pragma unroll
    for (int t = 0; t < 2; ++t) {
      bf16x8 kf = *(const bf16x8*)&Ks[cur][(t * 32 + l31) * 64 +
                      ((hi5 ^ (l31 & 7)) * 8)];
      sacc[t] = __builtin_amdgcn_mfma_f32_32x32x16_bf16(kf, qf[0], cinit, 0, 0, 0);
    }
#pragma unroll
    for (int ks16 = 1; ks16 < 4; ++ks16) {
#pragma unroll
      for (int t = 0; t < 2; ++t) {
        bf16x8 kf = *(const bf16x8*)&Ks[cur][(t * 32 + l31) * 64 +
                        (((ks16 * 2 + hi5) ^ (l31 & 7)) * 8)];
        sacc[t] = __builtin_amdgcn_mfma_f32_32x32x16_bf16(kf, qf[ks16], sacc[t], 0, 0, 0);
      }
    }
    __builtin_amdgcn_s_setprio(0);
    asm volatile("" : "+v"(sacc[0]), "+v"(sacc[1]));

#pragma unroll
    for (int t = 0; t < 2; ++t)
#pragma unroll
      for (int r = 0; r < 16; ++r)
        sacc[t][r] = __builtin_amdgcn_exp2f(sacc[t][r]);
#pragma unroll
    for (int r = 0; r < 4; ++r)
      l8[r] += (sacc[0][r] + sacc[0][r + 8]) + (sacc[1][r] + sacc[1][r + 8]);
#pragma unroll
    for (int r = 4; r < 8; ++r)
      l8[r] += (sacc[0][r] + sacc[0][r + 8]) + (sacc[1][r] + sacc[1][r + 8]);

    uint32_t wpk[16];
#pragma unroll
    for (int t = 0; t < 2; ++t) {
      union { __bf16 h[16]; uint32_t u[8]; } pk;
#pragma unroll
      for (int r = 0; r < 16; ++r) pk.h[r] = (__bf16)sacc[t][r];
#pragma unroll
      for (int j = 0; j < 8; ++j) wpk[t * 8 + j] = pk.u[j];
    }
    uint32_t xw[8];
#pragma unroll
    for (int t = 0; t < 2; ++t) {
      xw[t * 4 + 0] = __shfl_xor(hi5 ? wpk[t * 8 + 0] : wpk[t * 8 + 2], 32);
      xw[t * 4 + 1] = __shfl_xor(hi5 ? wpk[t * 8 + 1] : wpk[t * 8 + 3], 32);
      xw[t * 4 + 2] = __shfl_xor(hi5 ? wpk[t * 8 + 4] : wpk[t * 8 + 6], 32);
      xw[t * 4 + 3] = __shfl_xor(hi5 ? wpk[t * 8 + 5] : wpk[t * 8 + 7], 32);
    }

    __builtin_amdgcn_s_setprio(1);
#pragma unroll
    for (int ks = 0; ks < 4; ++ks) {
      const int t = ks >> 1, b = (ks & 1) * 4, o = t * 8, xb = t * 4 + (ks & 1) * 2;
      union { uint32_t u[4]; bf16x8 v; } pu;
      pu.u[0] = hi5 ? xw[xb] : wpk[o + b];
      pu.u[1] = hi5 ? xw[xb + 1] : wpk[o + b + 1];
      pu.u[2] = hi5 ? wpk[o + b + 2] : xw[xb];
      pu.u[3] = hi5 ? wpk[o + b + 3] : xw[xb + 1];
#pragma unroll
      for (int dt = 0; dt < 2; ++dt) {
        bf16x8 vf = *(const bf16x8*)&Vs[cur][(dt * 32 + l31) * 64 +
                        (((ks * 2 + hi5) ^ (l31 & 7)) * 8)];
        oacc[dt] = __builtin_amdgcn_mfma_f32_32x32x16_bf16(vf, pu.v, oacc[dt], 0, 0, 0);
      }
    }
    __builtin_amdgcn_s_setprio(0);
    __syncthreads();
  }

  float l = ((l8[0] + l8[4]) + (l8[1] + l8[5])) +
            ((l8[2] + l8[6]) + (l8[3] + l8[7]));
  l += __shfl_xor(l, 32);

  const float il = 1.0f / l;
  unsigned short* bw = &Ks[0][0] + w * 2048;
#pragma unroll
  for (int dt = 0; dt < 2; ++dt)
#pragma unroll
    for (int j = 0; j < 8; ++j) {
      const int dl = (j & 1) * 2 + (j >> 1) * 8 + hi5 * 4;
      const int d = dt * 32 + dl;
      const uint32_t pk = (uint32_t)f2bf(oacc[dt][2 * j] * il) |
                          ((uint32_t)f2bf(oacc[dt][2 * j + 1] * il) << 16);
      const int g = d >> 3, gi = (d >> 1) & 3;
      *(uint32_t*)&bw[l31 * 64 + ((g ^ (l31 & 7)) * 8) + gi * 2] = pk;
    }
  __syncthreads();
  const int bb = bh >> 4, hd = bh & 15;
#pragma unroll
  for (int i = 0; i < 4; ++i) {
    const int row = i * 8 + (lane >> 3);
    const int g = lane & 7;
    bf16x8 vv = *(const bf16x8*)&bw[row * 64 + ((g ^ (row & 7)) * 8)];
    *(bf16x8*)&At[((size_t)bb * TT + q0 + row) * CC + hd * DH + g * 8] = vv;
  }
}

extern "C" void kernel_launch(void* const* d_in, const int* in_sizes, int n_in,
                              void* d_out, int out_size, void* d_ws, size_t ws_size,
                              hipStream_t stream) {
  const float* x = (const float*)d_in[0];
  const float* Wqkv = (const float*)d_in[1];
  const float* bqkv = (const float*)d_in[2];
  const float* Wout = (const float*)d_in[3];
  const float* bout = (const float*)d_in[4];
  float* out = (float*)d_out;

  char* ws = (char*)d_ws;
  unsigned short* Xb  = (unsigned short*)(ws);                      // 16 MB
  unsigned short* WqT = (unsigned short*)(ws + (16ull << 20));      // 6 MB
  unsigned short* WoT = (unsigned short*)(ws + (22ull << 20));      // 2 MB
  unsigned short* Qb  = (unsigned short*)(ws + (24ull << 20));      // 16 MB
  unsigned short* Kb  = (unsigned short*)(ws + (40ull << 20));      // 16 MB
  unsigned short* Vt  = (unsigned short*)(ws + (56ull << 20));      // 16 MB
  unsigned short* At  = (unsigned short*)(ws + (72ull << 20));      // 16 MB (88 total)

  k_cvt<<<dim3((MM * KK) / (256 * 8)), 256, 0, stream>>>(x, Xb);
  k_tcvt<<<dim3(N1 / 32, KK / 32), 256, 0, stream>>>(Wqkv, WqT, KK, N1);
  k_tcvt<<<dim3(CC / 32, KK / 32), 256, 0, stream>>>(Wout, WoT, KK, CC);
  k_gemm2t<0, 24><<<dim3((MM / 128) * (N1 / 128)), 256, 0, stream>>>(
      Xb, WqT, bqkv, MM, N1, KK, Qb, Kb, Vt, nullptr);
  k_attn<<<dim3(BB * HH * (TT / 128)), 256, 0, stream>>>(Qb, Kb, Vt, At, -16.0f);
  k_gemm2t<1, 8><<<dim3((MM / 128) * (CC / 128)), 256, 0, stream>>>(
      At, WoT, bout, MM, CC, KK, nullptr, nullptr, nullptr, out);
}